// Round 1
// baseline (391.602 us; speedup 1.0000x reference)
//
#include <hip/hip_runtime.h>
#include <hip/hip_bf16.h>
#include <stdint.h>

// Problem dims
#define B_  16
#define T_  2048
#define D_  512
#define I_  1024
#define K_  31
#define M_  (B_ * T_)   // 32768

typedef __attribute__((ext_vector_type(8))) __bf16 bf16x8;
typedef __attribute__((ext_vector_type(4))) float  f32x4;

__device__ __forceinline__ unsigned short f2bf(float f) {
    union { float f; uint32_t u; } v; v.f = f;
    uint32_t u = v.u;
    uint32_t r = (u + 0x7FFFu + ((u >> 16) & 1u)) >> 16;
    return (unsigned short)r;
}
__device__ __forceinline__ float bf2f(unsigned short h) {
    union { uint32_t u; float f; } v; v.u = ((uint32_t)h) << 16;
    return v.f;
}

__device__ __forceinline__ void gload_lds16(const void* g, void* l) {
    __builtin_amdgcn_global_load_lds(
        (const __attribute__((address_space(1))) unsigned int*)g,
        (__attribute__((address_space(3))) unsigned int*)l, 16, 0, 0);
}

// ---------------- prep: cast weights to bf16 ----------------
__global__ __launch_bounds__(256) void prep_weights(
    const float* __restrict__ w1, const float* __restrict__ w2,
    unsigned short* __restrict__ w1b, unsigned short* __restrict__ w2b)
{
    int i = blockIdx.x * 256 + threadIdx.x;
    const int n1 = 2 * I_ * D_;   // 1048576
    const int n2 = D_ * I_;       // 524288
    if (i < n1) w1b[i] = f2bf(w1[i]);
    if (i < n2) w2b[i] = f2bf(w2[i]);
}

// ---------------- LayerNorm: fp32 -> bf16 xn ----------------
__global__ __launch_bounds__(256) void ln_kernel(
    const float* __restrict__ x, const float* __restrict__ gam,
    const float* __restrict__ bet, unsigned short* __restrict__ xn)
{
    int row  = blockIdx.x * 4 + (threadIdx.x >> 6);
    int lane = threadIdx.x & 63;
    const float* xr = x + (size_t)row * D_ + lane * 8;
    float4 a0 = *(const float4*)xr;
    float4 a1 = *(const float4*)(xr + 4);
    float xs[8] = {a0.x, a0.y, a0.z, a0.w, a1.x, a1.y, a1.z, a1.w};

    float s = xs[0]+xs[1]+xs[2]+xs[3]+xs[4]+xs[5]+xs[6]+xs[7];
    #pragma unroll
    for (int off = 32; off; off >>= 1) s += __shfl_xor(s, off);
    float mu = s * (1.0f / D_);

    float q = 0.f;
    #pragma unroll
    for (int j = 0; j < 8; ++j) { float d = xs[j] - mu; q += d * d; }
    #pragma unroll
    for (int off = 32; off; off >>= 1) q += __shfl_xor(q, off);
    float rstd = rsqrtf(q * (1.0f / D_) + 1e-5f);

    float4 g0 = *(const float4*)(gam + lane * 8);
    float4 g1 = *(const float4*)(gam + lane * 8 + 4);
    float4 e0 = *(const float4*)(bet + lane * 8);
    float4 e1 = *(const float4*)(bet + lane * 8 + 4);
    float gs[8] = {g0.x, g0.y, g0.z, g0.w, g1.x, g1.y, g1.z, g1.w};
    float bs[8] = {e0.x, e0.y, e0.z, e0.w, e1.x, e1.y, e1.z, e1.w};

    unsigned short o[8];
    #pragma unroll
    for (int j = 0; j < 8; ++j) o[j] = f2bf((xs[j] - mu) * rstd * gs[j] + bs[j]);
    uint4 pk;
    pk.x = (uint32_t)o[0] | ((uint32_t)o[1] << 16);
    pk.y = (uint32_t)o[2] | ((uint32_t)o[3] << 16);
    pk.z = (uint32_t)o[4] | ((uint32_t)o[5] << 16);
    pk.w = (uint32_t)o[6] | ((uint32_t)o[7] << 16);
    *(uint4*)(xn + (size_t)row * D_ + lane * 8) = pk;
}

// ---------------- GEMM1: xn[32768,512] x w1b^T -> SwiGLU -> u bf16 [32768,1024]
// Block tile: 128 rows x (64 a-cols + 64 g-cols). 4 waves, each 32 rows x 128 cols.
__global__ __launch_bounds__(256) void gemm1_kernel(
    const unsigned short* __restrict__ xn,   // [32768][512]
    const unsigned short* __restrict__ w1b,  // [2048][512]
    const float* __restrict__ b1,            // [2048]
    unsigned short* __restrict__ u)          // [32768][1024]
{
    __shared__ __align__(16) unsigned short As[128 * 64];
    __shared__ __align__(16) unsigned short Bs[128 * 64];
    const int tid  = threadIdx.x;
    const int m0   = blockIdx.x * 128;   // 256 m-blocks
    const int jb   = blockIdx.y;         // 16 channel blocks of 64
    const int wave = tid >> 6, lane = tid & 63;

    f32x4 acc[2][8];
    #pragma unroll
    for (int i = 0; i < 2; ++i)
        #pragma unroll
        for (int j = 0; j < 8; ++j) acc[i][j] = (f32x4){0.f, 0.f, 0.f, 0.f};

    for (int kt = 0; kt < 8; ++kt) {
        int k0 = kt * 64;
        #pragma unroll
        for (int ch = 0; ch < 4; ++ch) {
            int o   = tid * 16 + ch * 4096;
            int row = o >> 7;
            int col = (o & 127) >> 1;
            gload_lds16(xn + (size_t)(m0 + row) * D_ + k0 + col, (char*)As + o);
            int wrow = (row < 64) ? (jb * 64 + row) : (1024 + jb * 64 + row - 64);
            gload_lds16(w1b + (size_t)wrow * D_ + k0 + col, (char*)Bs + o);
        }
        __syncthreads();
        #pragma unroll
        for (int ks = 0; ks < 2; ++ks) {
            const int kb = ks * 64 + (lane >> 4) * 16;  // byte offset in row
            bf16x8 af[2], bfr[8];
            #pragma unroll
            for (int mf = 0; mf < 2; ++mf) {
                int r = wave * 32 + mf * 16 + (lane & 15);
                af[mf] = *(const bf16x8*)((const char*)As + r * 128 + kb);
            }
            #pragma unroll
            for (int nf = 0; nf < 8; ++nf) {
                int r = nf * 16 + (lane & 15);
                bfr[nf] = *(const bf16x8*)((const char*)Bs + r * 128 + kb);
            }
            #pragma unroll
            for (int mf = 0; mf < 2; ++mf)
                #pragma unroll
                for (int nf = 0; nf < 8; ++nf)
                    acc[mf][nf] = __builtin_amdgcn_mfma_f32_16x16x32_bf16(
                        af[mf], bfr[nf], acc[mf][nf], 0, 0, 0);
        }
        __syncthreads();
    }

    // epilogue: SwiGLU pairing acc[.][nf] (a) with acc[.][nf+4] (g)
    const int cL = lane & 15;
    const int rL = (lane >> 4) * 4;
    #pragma unroll
    for (int nf = 0; nf < 4; ++nf) {
        int ch = jb * 64 + nf * 16 + cL;
        float ba = b1[ch];
        float bg = b1[1024 + ch];
        #pragma unroll
        for (int mf = 0; mf < 2; ++mf) {
            #pragma unroll
            for (int r = 0; r < 4; ++r) {
                float a = acc[mf][nf][r] + ba;
                float g = acc[mf][nf + 4][r] + bg;
                float sg = g / (1.0f + __expf(-g));
                int row = m0 + wave * 32 + mf * 16 + rL + r;
                u[(size_t)row * I_ + ch] = f2bf(a * sg);
            }
        }
    }
}

// ---------------- depthwise conv K=31 + bias + PReLU: u bf16 -> v bf16 ----------------
__global__ __launch_bounds__(256) void dwconv_kernel(
    const unsigned short* __restrict__ u, const float* __restrict__ dw,
    const float* __restrict__ dwb, const float* __restrict__ alpha,
    unsigned short* __restrict__ v)
{
    // grid: x = T/64 = 32, y = I/64 = 16, z = B = 16
    const int lane = threadIdx.x & 63;
    const int warp = threadIdx.x >> 6;
    const int c  = blockIdx.y * 64 + lane;
    const int b  = blockIdx.z;
    const int t0 = blockIdx.x * 64 + warp * 16;

    float dwk[K_];
    #pragma unroll
    for (int k = 0; k < K_; ++k) dwk[k] = dw[c * K_ + k];

    const unsigned short* ub = u + ((size_t)b * T_) * I_ + c;
    float w[46];
    #pragma unroll
    for (int j = 0; j < 46; ++j) {
        int tt = t0 - 15 + j;
        w[j] = (tt >= 0 && tt < T_) ? bf2f(ub[(size_t)tt * I_]) : 0.0f;
    }

    const float bia = dwb[c], al = alpha[c];
    unsigned short* vb = v + ((size_t)b * T_ + t0) * I_ + c;
    #pragma unroll
    for (int i = 0; i < 16; ++i) {
        float acc = bia;
        #pragma unroll
        for (int k = 0; k < K_; ++k) acc += w[i + k] * dwk[k];
        float o = acc > 0.f ? acc : al * acc;
        vb[(size_t)i * I_] = f2bf(o);
    }
}

// ---------------- GEMM2: v[32768,1024] x w2b^T + b2 -> out fp32 [32768,512] ----------------
__global__ __launch_bounds__(256) void gemm2_kernel(
    const unsigned short* __restrict__ v,    // [32768][1024]
    const unsigned short* __restrict__ w2b,  // [512][1024]
    const float* __restrict__ b2,            // [512]
    float* __restrict__ out)                 // [32768][512]
{
    __shared__ __align__(16) unsigned short As[128 * 64];
    __shared__ __align__(16) unsigned short Bs[128 * 64];
    const int tid  = threadIdx.x;
    const int m0   = blockIdx.x * 128;  // 256
    const int n0   = blockIdx.y * 128;  // 4
    const int wave = tid >> 6, lane = tid & 63;
    const int wr = (wave >> 1) * 64, wc = (wave & 1) * 64;

    f32x4 acc[4][4];
    #pragma unroll
    for (int i = 0; i < 4; ++i)
        #pragma unroll
        for (int j = 0; j < 4; ++j) acc[i][j] = (f32x4){0.f, 0.f, 0.f, 0.f};

    for (int kt = 0; kt < 16; ++kt) {
        int k0 = kt * 64;
        #pragma unroll
        for (int ch = 0; ch < 4; ++ch) {
            int o   = tid * 16 + ch * 4096;
            int row = o >> 7;
            int col = (o & 127) >> 1;
            gload_lds16(v   + (size_t)(m0 + row) * I_ + k0 + col, (char*)As + o);
            gload_lds16(w2b + (size_t)(n0 + row) * I_ + k0 + col, (char*)Bs + o);
        }
        __syncthreads();
        #pragma unroll
        for (int ks = 0; ks < 2; ++ks) {
            const int kb = ks * 64 + (lane >> 4) * 16;
            bf16x8 af[4], bfr[4];
            #pragma unroll
            for (int mf = 0; mf < 4; ++mf) {
                int r = wr + mf * 16 + (lane & 15);
                af[mf] = *(const bf16x8*)((const char*)As + r * 128 + kb);
            }
            #pragma unroll
            for (int nf = 0; nf < 4; ++nf) {
                int r = wc + nf * 16 + (lane & 15);
                bfr[nf] = *(const bf16x8*)((const char*)Bs + r * 128 + kb);
            }
            #pragma unroll
            for (int mf = 0; mf < 4; ++mf)
                #pragma unroll
                for (int nf = 0; nf < 4; ++nf)
                    acc[mf][nf] = __builtin_amdgcn_mfma_f32_16x16x32_bf16(
                        af[mf], bfr[nf], acc[mf][nf], 0, 0, 0);
        }
        __syncthreads();
    }

    const int cL = lane & 15;
    const int rL = (lane >> 4) * 4;
    #pragma unroll
    for (int nf = 0; nf < 4; ++nf) {
        int col = n0 + wc + nf * 16 + cL;
        float bb = b2[col];
        #pragma unroll
        for (int mf = 0; mf < 4; ++mf) {
            #pragma unroll
            for (int r = 0; r < 4; ++r) {
                int row = m0 + wr + mf * 16 + rL + r;
                out[(size_t)row * D_ + col] = acc[mf][nf][r] + bb;
            }
        }
    }
}

extern "C" void kernel_launch(void* const* d_in, const int* in_sizes, int n_in,
                              void* d_out, int out_size, void* d_ws, size_t ws_size,
                              hipStream_t stream) {
    const float* x     = (const float*)d_in[0];
    const float* ln_g  = (const float*)d_in[1];
    const float* ln_b  = (const float*)d_in[2];
    const float* w1    = (const float*)d_in[3];
    const float* b1    = (const float*)d_in[4];
    const float* dw    = (const float*)d_in[5];
    const float* dwb   = (const float*)d_in[6];
    const float* alpha = (const float*)d_in[7];
    const float* w2    = (const float*)d_in[8];
    const float* b2    = (const float*)d_in[9];
    float* out = (float*)d_out;

    char* ws = (char*)d_ws;
    unsigned short* xn  = (unsigned short*)(ws);                 // 32 MB
    unsigned short* u   = (unsigned short*)(ws + 33554432);      // 64 MB
    unsigned short* v   = (unsigned short*)(ws + 100663296);     // 64 MB
    unsigned short* w1b = (unsigned short*)(ws + 167772160);     // 2 MB
    unsigned short* w2b = (unsigned short*)(ws + 169869312);     // 1 MB

    prep_weights<<<4096, 256, 0, stream>>>(w1, w2, w1b, w2b);
    ln_kernel<<<M_ / 4, 256, 0, stream>>>(x, ln_g, ln_b, xn);
    dim3 g1(M_ / 128, I_ / 64);               // (256, 16)
    gemm1_kernel<<<g1, 256, 0, stream>>>(xn, w1b, b1, u);
    dim3 gc(T_ / 64, I_ / 64, B_);            // (32, 16, 16)
    dwconv_kernel<<<gc, 256, 0, stream>>>(u, dw, dwb, alpha, v);
    dim3 g2(M_ / 128, D_ / 128);              // (256, 4)
    gemm2_kernel<<<g2, 256, 0, stream>>>(v, w2b, b2, out);
}

// Round 2
// 263.603 us; speedup vs baseline: 1.4856x; 1.4856x over previous
//
#include <hip/hip_runtime.h>
#include <hip/hip_bf16.h>
#include <stdint.h>

// Problem dims
#define B_  16
#define T_  2048
#define D_  512
#define I_  1024
#define K_  31
#define M_  (B_ * T_)   // 32768

typedef __attribute__((ext_vector_type(8))) __bf16 bf16x8;
typedef __attribute__((ext_vector_type(4))) float  f32x4;

__device__ __forceinline__ unsigned short f2bf(float f) {
    union { float f; uint32_t u; } v; v.f = f;
    uint32_t u = v.u;
    uint32_t r = (u + 0x7FFFu + ((u >> 16) & 1u)) >> 16;
    return (unsigned short)r;
}
__device__ __forceinline__ float bf2f(unsigned short h) {
    union { uint32_t u; float f; } v; v.u = ((uint32_t)h) << 16;
    return v.f;
}

__device__ __forceinline__ void gload_lds16(const void* g, void* l) {
    __builtin_amdgcn_global_load_lds(
        (const __attribute__((address_space(1))) unsigned int*)g,
        (__attribute__((address_space(3))) unsigned int*)l, 16, 0, 0);
}

// ---------------- prep: cast weights to bf16 ----------------
__global__ __launch_bounds__(256) void prep_weights(
    const float* __restrict__ w1, const float* __restrict__ w2,
    unsigned short* __restrict__ w1b, unsigned short* __restrict__ w2b)
{
    int i = blockIdx.x * 256 + threadIdx.x;
    const int n1 = 2 * I_ * D_;   // 1048576
    const int n2 = D_ * I_;       // 524288
    if (i < n1) w1b[i] = f2bf(w1[i]);
    if (i < n2) w2b[i] = f2bf(w2[i]);
}

// ---------------- LayerNorm: fp32 -> bf16 xn ----------------
__global__ __launch_bounds__(256) void ln_kernel(
    const float* __restrict__ x, const float* __restrict__ gam,
    const float* __restrict__ bet, unsigned short* __restrict__ xn)
{
    int row  = blockIdx.x * 4 + (threadIdx.x >> 6);
    int lane = threadIdx.x & 63;
    const float* xr = x + (size_t)row * D_ + lane * 8;
    float4 a0 = *(const float4*)xr;
    float4 a1 = *(const float4*)(xr + 4);
    float xs[8] = {a0.x, a0.y, a0.z, a0.w, a1.x, a1.y, a1.z, a1.w};

    float s = xs[0]+xs[1]+xs[2]+xs[3]+xs[4]+xs[5]+xs[6]+xs[7];
    #pragma unroll
    for (int off = 32; off; off >>= 1) s += __shfl_xor(s, off);
    float mu = s * (1.0f / D_);

    float q = 0.f;
    #pragma unroll
    for (int j = 0; j < 8; ++j) { float d = xs[j] - mu; q += d * d; }
    #pragma unroll
    for (int off = 32; off; off >>= 1) q += __shfl_xor(q, off);
    float rstd = rsqrtf(q * (1.0f / D_) + 1e-5f);

    float4 g0 = *(const float4*)(gam + lane * 8);
    float4 g1 = *(const float4*)(gam + lane * 8 + 4);
    float4 e0 = *(const float4*)(bet + lane * 8);
    float4 e1 = *(const float4*)(bet + lane * 8 + 4);
    float gs[8] = {g0.x, g0.y, g0.z, g0.w, g1.x, g1.y, g1.z, g1.w};
    float bs[8] = {e0.x, e0.y, e0.z, e0.w, e1.x, e1.y, e1.z, e1.w};

    unsigned short o[8];
    #pragma unroll
    for (int j = 0; j < 8; ++j) o[j] = f2bf((xs[j] - mu) * rstd * gs[j] + bs[j]);
    uint4 pk;
    pk.x = (uint32_t)o[0] | ((uint32_t)o[1] << 16);
    pk.y = (uint32_t)o[2] | ((uint32_t)o[3] << 16);
    pk.z = (uint32_t)o[4] | ((uint32_t)o[5] << 16);
    pk.w = (uint32_t)o[6] | ((uint32_t)o[7] << 16);
    *(uint4*)(xn + (size_t)row * D_ + lane * 8) = pk;
}

// ---------------- GEMM1: xn[32768,512] x w1b^T -> SwiGLU -> u bf16 [32768,1024]
// Block tile: 128 rows x (64 a-cols + 64 g-cols). 4 waves, each 32 rows x 128 cols.
__global__ __launch_bounds__(256) void gemm1_kernel(
    const unsigned short* __restrict__ xn,   // [32768][512]
    const unsigned short* __restrict__ w1b,  // [2048][512]
    const float* __restrict__ b1,            // [2048]
    unsigned short* __restrict__ u)          // [32768][1024]
{
    __shared__ __align__(16) unsigned short As[128 * 64];
    __shared__ __align__(16) unsigned short Bs[128 * 64];
    const int tid  = threadIdx.x;
    const int m0   = blockIdx.x * 128;   // 256 m-blocks
    const int jb   = blockIdx.y;         // 16 channel blocks of 64
    const int wave = tid >> 6, lane = tid & 63;

    f32x4 acc[2][8];
    #pragma unroll
    for (int i = 0; i < 2; ++i)
        #pragma unroll
        for (int j = 0; j < 8; ++j) acc[i][j] = (f32x4){0.f, 0.f, 0.f, 0.f};

    for (int kt = 0; kt < 8; ++kt) {
        int k0 = kt * 64;
        #pragma unroll
        for (int ch = 0; ch < 4; ++ch) {
            int o   = tid * 16 + ch * 4096;
            int row = o >> 7;
            int col = (o & 127) >> 1;
            gload_lds16(xn + (size_t)(m0 + row) * D_ + k0 + col, (char*)As + o);
            int wrow = (row < 64) ? (jb * 64 + row) : (1024 + jb * 64 + row - 64);
            gload_lds16(w1b + (size_t)wrow * D_ + k0 + col, (char*)Bs + o);
        }
        __syncthreads();
        #pragma unroll
        for (int ks = 0; ks < 2; ++ks) {
            const int kb = ks * 64 + (lane >> 4) * 16;  // byte offset in row
            bf16x8 af[2], bfr[8];
            #pragma unroll
            for (int mf = 0; mf < 2; ++mf) {
                int r = wave * 32 + mf * 16 + (lane & 15);
                af[mf] = *(const bf16x8*)((const char*)As + r * 128 + kb);
            }
            #pragma unroll
            for (int nf = 0; nf < 8; ++nf) {
                int r = nf * 16 + (lane & 15);
                bfr[nf] = *(const bf16x8*)((const char*)Bs + r * 128 + kb);
            }
            #pragma unroll
            for (int mf = 0; mf < 2; ++mf)
                #pragma unroll
                for (int nf = 0; nf < 8; ++nf)
                    acc[mf][nf] = __builtin_amdgcn_mfma_f32_16x16x32_bf16(
                        af[mf], bfr[nf], acc[mf][nf], 0, 0, 0);
        }
        __syncthreads();
    }

    // epilogue: SwiGLU pairing acc[.][nf] (a) with acc[.][nf+4] (g)
    const int cL = lane & 15;
    const int rL = (lane >> 4) * 4;
    #pragma unroll
    for (int nf = 0; nf < 4; ++nf) {
        int ch = jb * 64 + nf * 16 + cL;
        float ba = b1[ch];
        float bg = b1[1024 + ch];
        #pragma unroll
        for (int mf = 0; mf < 2; ++mf) {
            #pragma unroll
            for (int r = 0; r < 4; ++r) {
                float a = acc[mf][nf][r] + ba;
                float g = acc[mf][nf + 4][r] + bg;
                float sg = g / (1.0f + __expf(-g));
                int row = m0 + wave * 32 + mf * 16 + rL + r;
                u[(size_t)row * I_ + ch] = f2bf(a * sg);
            }
        }
    }
}

// ---------------- depthwise conv K=31 + bias + PReLU: u bf16 -> v bf16 ----------------
// LDS-staged: block = 64 channels x 256 t-outputs (+30 halo), one batch.
__global__ __launch_bounds__(256) void dwconv_kernel(
    const unsigned short* __restrict__ u, const float* __restrict__ dw,
    const float* __restrict__ dwb, const float* __restrict__ alpha,
    unsigned short* __restrict__ v)
{
    // grid: x = T/256 = 8, y = I/64 = 16, z = B = 16
    __shared__ __align__(16) unsigned short su[286][64];
    const int tid     = threadIdx.x;
    const int c0      = blockIdx.y * 64;
    const int b       = blockIdx.z;
    const int tile_t0 = blockIdx.x * 256;

    // stage [tile_t0-15, tile_t0+270] x [c0, c0+63] into LDS, zero-filled halo
    #pragma unroll
    for (int it = 0; it < 9; ++it) {
        int r = it * 32 + (tid >> 3);
        if (r < 286) {
            int tt = tile_t0 - 15 + r;
            int cc = (tid & 7) * 8;
            uint4 val = {0u, 0u, 0u, 0u};
            if (tt >= 0 && tt < T_)
                val = *(const uint4*)(u + ((size_t)b * T_ + tt) * I_ + c0 + cc);
            *(uint4*)(&su[r][cc]) = val;
        }
    }
    __syncthreads();

    const int c  = tid & 63;          // channel within block
    const int tb = (tid >> 6) * 64;   // 64 outputs per thread

    float dwk[K_];
    #pragma unroll
    for (int k = 0; k < K_; ++k) dwk[k] = dw[(c0 + c) * K_ + k];
    const float bia = dwb[c0 + c], al = alpha[c0 + c];

    unsigned short* vb = v + ((size_t)b * T_ + tile_t0 + tb) * I_ + c0 + c;

    #pragma unroll
    for (int chk = 0; chk < 4; ++chk) {
        float w[46];
        #pragma unroll
        for (int j = 0; j < 46; ++j)
            w[j] = bf2f(su[tb + chk * 16 + j][c]);
        #pragma unroll
        for (int i = 0; i < 16; ++i) {
            float acc = bia;
            #pragma unroll
            for (int k = 0; k < K_; ++k) acc += w[i + k] * dwk[k];
            float o = acc > 0.f ? acc : al * acc;
            vb[(size_t)(chk * 16 + i) * I_] = f2bf(o);
        }
    }
}

// ---------------- GEMM2: v[32768,1024] x w2b^T + b2 -> out fp32 [32768,512] ----------------
__global__ __launch_bounds__(256) void gemm2_kernel(
    const unsigned short* __restrict__ v,    // [32768][1024]
    const unsigned short* __restrict__ w2b,  // [512][1024]
    const float* __restrict__ b2,            // [512]
    float* __restrict__ out)                 // [32768][512]
{
    __shared__ __align__(16) unsigned short As[128 * 64];
    __shared__ __align__(16) unsigned short Bs[128 * 64];
    const int tid  = threadIdx.x;
    const int m0   = blockIdx.x * 128;  // 256
    const int n0   = blockIdx.y * 128;  // 4
    const int wave = tid >> 6, lane = tid & 63;
    const int wr = (wave >> 1) * 64, wc = (wave & 1) * 64;

    f32x4 acc[4][4];
    #pragma unroll
    for (int i = 0; i < 4; ++i)
        #pragma unroll
        for (int j = 0; j < 4; ++j) acc[i][j] = (f32x4){0.f, 0.f, 0.f, 0.f};

    for (int kt = 0; kt < 16; ++kt) {
        int k0 = kt * 64;
        #pragma unroll
        for (int ch = 0; ch < 4; ++ch) {
            int o   = tid * 16 + ch * 4096;
            int row = o >> 7;
            int col = (o & 127) >> 1;
            gload_lds16(v   + (size_t)(m0 + row) * I_ + k0 + col, (char*)As + o);
            gload_lds16(w2b + (size_t)(n0 + row) * I_ + k0 + col, (char*)Bs + o);
        }
        __syncthreads();
        #pragma unroll
        for (int ks = 0; ks < 2; ++ks) {
            const int kb = ks * 64 + (lane >> 4) * 16;
            bf16x8 af[4], bfr[4];
            #pragma unroll
            for (int mf = 0; mf < 4; ++mf) {
                int r = wr + mf * 16 + (lane & 15);
                af[mf] = *(const bf16x8*)((const char*)As + r * 128 + kb);
            }
            #pragma unroll
            for (int nf = 0; nf < 4; ++nf) {
                int r = wc + nf * 16 + (lane & 15);
                bfr[nf] = *(const bf16x8*)((const char*)Bs + r * 128 + kb);
            }
            #pragma unroll
            for (int mf = 0; mf < 4; ++mf)
                #pragma unroll
                for (int nf = 0; nf < 4; ++nf)
                    acc[mf][nf] = __builtin_amdgcn_mfma_f32_16x16x32_bf16(
                        af[mf], bfr[nf], acc[mf][nf], 0, 0, 0);
        }
        __syncthreads();
    }

    const int cL = lane & 15;
    const int rL = (lane >> 4) * 4;
    #pragma unroll
    for (int nf = 0; nf < 4; ++nf) {
        int col = n0 + wc + nf * 16 + cL;
        float bb = b2[col];
        #pragma unroll
        for (int mf = 0; mf < 4; ++mf) {
            #pragma unroll
            for (int r = 0; r < 4; ++r) {
                int row = m0 + wr + mf * 16 + rL + r;
                out[(size_t)row * D_ + col] = acc[mf][nf][r] + bb;
            }
        }
    }
}

extern "C" void kernel_launch(void* const* d_in, const int* in_sizes, int n_in,
                              void* d_out, int out_size, void* d_ws, size_t ws_size,
                              hipStream_t stream) {
    const float* x     = (const float*)d_in[0];
    const float* ln_g  = (const float*)d_in[1];
    const float* ln_b  = (const float*)d_in[2];
    const float* w1    = (const float*)d_in[3];
    const float* b1    = (const float*)d_in[4];
    const float* dw    = (const float*)d_in[5];
    const float* dwb   = (const float*)d_in[6];
    const float* alpha = (const float*)d_in[7];
    const float* w2    = (const float*)d_in[8];
    const float* b2    = (const float*)d_in[9];
    float* out = (float*)d_out;

    char* ws = (char*)d_ws;
    unsigned short* xn  = (unsigned short*)(ws);                 // 32 MB
    unsigned short* u   = (unsigned short*)(ws + 33554432);      // 64 MB
    unsigned short* v   = (unsigned short*)(ws + 100663296);     // 64 MB
    unsigned short* w1b = (unsigned short*)(ws + 167772160);     // 2 MB
    unsigned short* w2b = (unsigned short*)(ws + 169869312);     // 1 MB

    prep_weights<<<4096, 256, 0, stream>>>(w1, w2, w1b, w2b);
    ln_kernel<<<M_ / 4, 256, 0, stream>>>(x, ln_g, ln_b, xn);
    dim3 g1(M_ / 128, I_ / 64);               // (256, 16)
    gemm1_kernel<<<g1, 256, 0, stream>>>(xn, w1b, b1, u);
    dim3 gc(T_ / 256, I_ / 64, B_);           // (8, 16, 16)
    dwconv_kernel<<<gc, 256, 0, stream>>>(u, dw, dwb, alpha, v);
    dim3 g2(M_ / 128, D_ / 128);              // (256, 4)
    gemm2_kernel<<<g2, 256, 0, stream>>>(v, w2b, b2, out);
}